// Round 12
// baseline (3310.792 us; speedup 1.0000x reference)
//
#include <hip/hip_runtime.h>
#include <hip/hip_fp16.h>

#define NB 8
#define CAP 128
#define NFEAT 704
#define MSLICE 8            // node slices per (batch,k) in moments
#define PSLICE (MSLICE * 4) // partial slots = slices * subs
#define NBLK 768            // persistent grid: 3 blocks/CU x 256 CUs, guaranteed co-resident
#define KS 2                // node sets per wave (each set = 4 nodes, one per 16-lane group)

// ---------------- setup kernels ----------------

__global__ void count_edges(const int* __restrict__ ei, int E, int* __restrict__ cnt) {
    int e = blockIdx.x * blockDim.x + threadIdx.x;
    if (e < E) atomicAdd(&cnt[ei[E + e]], 1);
}

__global__ void compute_dinv(const int* __restrict__ cnt, float* __restrict__ dinv, int n) {
    int v = blockIdx.x * blockDim.x + threadIdx.x;
    if (v < n) dinv[v] = rsqrtf((float)(cnt[v] + 1));  // +1 self-loop; always > 0
}

// packed edge: low 16 = src node (N < 65536), high 16 = f16 weight (always > 0)
__global__ void fill_edges(const int* __restrict__ ei, int E, const float* __restrict__ dinv,
                           int* __restrict__ cursor, unsigned int* __restrict__ pairs) {
    int e = blockIdx.x * blockDim.x + threadIdx.x;
    if (e < E) {
        int r = ei[e], c = ei[E + e];
        int pos = atomicAdd(&cursor[c], 1);
        if (pos < CAP) {
            float w = dinv[r] * dinv[c];
            __half hw = __float2half_rn(w);
            unsigned short hb = *reinterpret_cast<unsigned short*>(&hw);
            pairs[(size_t)c * CAP + pos] = (unsigned int)(r & 0xFFFF) | ((unsigned int)hb << 16);
        }
    }
}

// batch is SORTED: boundaries, no atomics
__global__ void batch_bounds(const int* __restrict__ batch, int n, int* __restrict__ boff) {
    int i = blockIdx.x * blockDim.x + threadIdx.x;
    if (i >= n) return;
    int b = batch[i];
    int pb = (i == 0) ? -1 : batch[i - 1];
    for (int k = pb + 1; k <= b; ++k) boff[k] = i;
    if (i == n - 1) {
        for (int k = b + 1; k <= NB; ++k) boff[k] = n;
    }
}

__global__ void convert_f16(const float* __restrict__ x, unsigned short* __restrict__ xh, int n) {
    int i = blockIdx.x * blockDim.x + threadIdx.x;
    if (i < n) {
        __half h = __float2half_rn(x[i]);
        xh[i] = *reinterpret_cast<unsigned short*>(&h);
    }
}

// ---------------- persistent cascade ----------------
// One kernel, 24 grid-steps with spin barriers:
//   t=1..8:   L1 steps 1..8   (snap t=1; diffs t=2,4,8 -> S1 slots 0..2 + S1h, birth L2 states)
//   t=9..16:  L1 steps 9..16 fused with L2 steps f=t-8=1..8
//   t=17..24: L2 steps f=9..16
// Wave owns KS*4 nodes: set tt, group g=lane>>4 -> node (wid*KS+tt)*4+g; the group's
// 16 lanes hold that node's 64 channels as quads (q=lane&15). fp32 state st[][4][4],
// prev pv[][4][4] live in REGISTERS for all 24 steps (unit 0 = L1, units 1..3 = L2
// wavelet blocks). Gathers read fp16 mirrors; mirrors + S1/S2 are the only state traffic.
// Barrier: monotone counter + __threadfence (wbl2/inv on gfx950) + safety cap.

__device__ __forceinline__ float h2f(unsigned short h) {
    __half hh = *reinterpret_cast<__half*>(&h);
    return __half2float(hh);
}

__device__ __forceinline__ uint2 pack4(float a, float b, float c, float d) {
    __half2 p0 = __float22half2_rn(make_float2(a, b));
    __half2 p1 = __float22half2_rn(make_float2(c, d));
    uint2 r;
    r.x = *reinterpret_cast<unsigned int*>(&p0);
    r.y = *reinterpret_cast<unsigned int*>(&p1);
    return r;
}

__device__ __forceinline__ void fma4(float w, uint2 m, float* a) {
    float2 f0 = __half22float2(*reinterpret_cast<__half2*>(&m.x));
    float2 f1 = __half22float2(*reinterpret_cast<__half2*>(&m.y));
    a[0] += w * f0.x; a[1] += w * f0.y; a[2] += w * f1.x; a[3] += w * f1.y;
}

__global__ __launch_bounds__(256, 3) void persist_k(
    const float* __restrict__ x, const unsigned short* __restrict__ xh,
    unsigned short* __restrict__ m1a, unsigned short* __restrict__ m1b,
    unsigned short* __restrict__ s1h,
    unsigned short* __restrict__ m2a, unsigned short* __restrict__ m2b,
    float* __restrict__ S1, float* __restrict__ S2,
    const unsigned int* __restrict__ pairs, const int* __restrict__ cnt,
    const float* __restrict__ dinv, int n, int* __restrict__ bar)
{
    const int wid = blockIdx.x * 4 + (threadIdx.x >> 6);
    const int lane = threadIdx.x & 63;
    const int g = lane >> 4, q = lane & 15;
    const long nu = (long)n * 64;

    int node[KS]; bool valid[KS]; int degc[KS]; float selfw[KS];
    int maxr = 0;
#pragma unroll
    for (int t = 0; t < KS; ++t) {
        node[t] = (wid * KS + t) * 4 + g;
        valid[t] = node[t] < n;
        degc[t] = valid[t] ? min(cnt[node[t]], CAP) : 0;
        float dv = valid[t] ? dinv[node[t]] : 0.f;
        selfw[t] = 1.f + dv * dv;
        maxr = max(maxr, degc[t]);
    }
    // wave-wide max rounds (values differ across groups only)
    maxr = max(maxr, __shfl_xor(maxr, 16, 64));
    maxr = max(maxr, __shfl_xor(maxr, 32, 64));

    float st[KS][4][4], pv[KS][4][4];
#pragma unroll
    for (int t = 0; t < KS; ++t) {
        if (valid[t]) {
            float4 xv = *reinterpret_cast<const float4*>(x + (size_t)node[t] * 64 + q * 4);
            st[t][0][0] = xv.x; st[t][0][1] = xv.y; st[t][0][2] = xv.z; st[t][0][3] = xv.w;
        }
    }

    for (int step = 1; step <= 24; ++step) {
        int f = step - 8;
        bool u1 = step <= 16;
        bool u2 = step >= 9;
        const unsigned short* m1r = (step == 1) ? xh : ((step & 1) ? m1b : m1a);
        unsigned short* m1w = (step & 1) ? m1a : m1b;
        const unsigned short* m2r = (f == 1) ? s1h : ((f & 1) ? m2b : m2a);
        unsigned short* m2w = (f & 1) ? m2a : m2b;

        float ac[KS][4][4];
#pragma unroll
        for (int t = 0; t < KS; ++t)
#pragma unroll
            for (int u = 0; u < 4; ++u)
#pragma unroll
                for (int k = 0; k < 4; ++k) ac[t][u][k] = 0.f;

#pragma unroll 2
        for (int j = 0; j < maxr; ++j) {
            unsigned int e[KS];
            int src[KS]; float w[KS];
#pragma unroll
            for (int t = 0; t < KS; ++t) {
                e[t] = (j < degc[t]) ? pairs[(size_t)node[t] * CAP + j] : 0u;
                src[t] = (int)(e[t] & 0xFFFFu);
                w[t] = h2f((unsigned short)(e[t] >> 16));
            }
            // issue all gathers, then all FMAs (w=0 rounds gather row 0: L2-hot, harmless)
            uint2 g1[KS], g2[KS][3];
            if (u1) {
#pragma unroll
                for (int t = 0; t < KS; ++t)
                    g1[t] = *reinterpret_cast<const uint2*>(m1r + (size_t)src[t] * 64 + q * 4);
            }
            if (u2) {
#pragma unroll
                for (int t = 0; t < KS; ++t)
#pragma unroll
                    for (int u = 0; u < 3; ++u)
                        g2[t][u] = *reinterpret_cast<const uint2*>(m2r + u * nu + (size_t)src[t] * 64 + q * 4);
            }
            if (u1) {
#pragma unroll
                for (int t = 0; t < KS; ++t) fma4(w[t], g1[t], ac[t][0]);
            }
            if (u2) {
#pragma unroll
                for (int t = 0; t < KS; ++t)
#pragma unroll
                    for (int u = 0; u < 3; ++u) fma4(w[t], g2[t][u], ac[t][1 + u]);
            }
        }

        // update + emit
#pragma unroll
        for (int t = 0; t < KS; ++t) {
            if (!valid[t]) continue;
            size_t rowo = (size_t)node[t] * 64 + q * 4;
            if (u1) {
                float v0 = 0.5f * (selfw[t] * st[t][0][0] + ac[t][0][0]);
                float v1 = 0.5f * (selfw[t] * st[t][0][1] + ac[t][0][1]);
                float v2 = 0.5f * (selfw[t] * st[t][0][2] + ac[t][0][2]);
                float v3 = 0.5f * (selfw[t] * st[t][0][3] + ac[t][0][3]);
                st[t][0][0] = v0; st[t][0][1] = v1; st[t][0][2] = v2; st[t][0][3] = v3;
                *reinterpret_cast<uint2*>(m1w + rowo) = pack4(v0, v1, v2, v3);
                if (step == 1) {
                    pv[t][0][0] = v0; pv[t][0][1] = v1; pv[t][0][2] = v2; pv[t][0][3] = v3;
                } else if (step == 2 || step == 4 || step == 8 || step == 16) {
                    float d0 = fabsf(v0 - pv[t][0][0]), d1 = fabsf(v1 - pv[t][0][1]);
                    float d2 = fabsf(v2 - pv[t][0][2]), d3 = fabsf(v3 - pv[t][0][3]);
                    pv[t][0][0] = v0; pv[t][0][1] = v1; pv[t][0][2] = v2; pv[t][0][3] = v3;
                    int slot = (step == 2) ? 0 : (step == 4) ? 1 : (step == 8) ? 2 : 3;
                    *reinterpret_cast<float4*>(S1 + (size_t)node[t] * 256 + slot * 64 + q * 4) =
                        make_float4(d0, d1, d2, d3);
                    if (step == 2) {
                        *reinterpret_cast<uint2*>(s1h + 0 * nu + rowo) = pack4(d0, d1, d2, d3);
                        st[t][1][0] = d0; st[t][1][1] = d1; st[t][1][2] = d2; st[t][1][3] = d3;
                    } else if (step == 4) {
                        *reinterpret_cast<uint2*>(s1h + 1 * nu + rowo) = pack4(d0, d1, d2, d3);
                        st[t][2][0] = d0; st[t][2][1] = d1; st[t][2][2] = d2; st[t][2][3] = d3;
                    } else if (step == 8) {
                        *reinterpret_cast<uint2*>(s1h + 2 * nu + rowo) = pack4(d0, d1, d2, d3);
                        st[t][3][0] = d0; st[t][3][1] = d1; st[t][3][2] = d2; st[t][3][3] = d3;
                    }
                }
            }
            if (u2) {
#pragma unroll
                for (int u = 0; u < 3; ++u) {
                    float v0 = 0.5f * (selfw[t] * st[t][1 + u][0] + ac[t][1 + u][0]);
                    float v1 = 0.5f * (selfw[t] * st[t][1 + u][1] + ac[t][1 + u][1]);
                    float v2 = 0.5f * (selfw[t] * st[t][1 + u][2] + ac[t][1 + u][2]);
                    float v3 = 0.5f * (selfw[t] * st[t][1 + u][3] + ac[t][1 + u][3]);
                    st[t][1 + u][0] = v0; st[t][1 + u][1] = v1;
                    st[t][1 + u][2] = v2; st[t][1 + u][3] = v3;
                    *reinterpret_cast<uint2*>(m2w + u * nu + rowo) = pack4(v0, v1, v2, v3);
                    int snap = 2 << u;
                    if (f == snap) {
                        pv[t][1 + u][0] = v0; pv[t][1 + u][1] = v1;
                        pv[t][1 + u][2] = v2; pv[t][1 + u][3] = v3;
                    } else if (f > snap && (f == 4 || f == 8 || f == 16)) {
                        float d0 = fabsf(v0 - pv[t][1 + u][0]), d1 = fabsf(v1 - pv[t][1 + u][1]);
                        float d2 = fabsf(v2 - pv[t][1 + u][2]), d3 = fabsf(v3 - pv[t][1 + u][3]);
                        pv[t][1 + u][0] = v0; pv[t][1 + u][1] = v1;
                        pv[t][1 + u][2] = v2; pv[t][1 + u][3] = v3;
                        int slt = (u == 0) ? ((f == 4) ? 0 : (f == 8) ? 1 : 3)
                                : (u == 1) ? ((f == 8) ? 2 : 4) : 5;
                        *reinterpret_cast<float4*>(S2 + (size_t)node[t] * 384 + slt * 64 + q * 4) =
                            make_float4(d0, d1, d2, d3);
                    }
                }
            }
        }

        // grid barrier (skip after final step)
        if (step < 24) {
            __syncthreads();
            if (threadIdx.x == 0) {
                __threadfence();                 // release: flush this block's stores (wbl2)
                atomicAdd(bar, 1);
                int target = NBLK * step;
                int it = 0;
                while (atomicAdd(bar, 0) < target) {
                    __builtin_amdgcn_s_sleep(16);
                    if (++it > 4000000) break;   // safety: fail clean rather than hang
                }
                __threadfence();                 // acquire: invalidate caches
            }
            __syncthreads();
        }
    }
}

// ---------------- moments (coalesced two-stage, no atomics) ----------------

__global__ __launch_bounds__(256) void moments_part(
    const float* __restrict__ x, const float* __restrict__ S1,
    const float* __restrict__ S2, const int* __restrict__ boff,
    double* __restrict__ part)
{
    int bid = blockIdx.x;                    // b * (11*MSLICE) + k * MSLICE + slice
    int slice = bid % MSLICE;
    int k = (bid / MSLICE) % 11;
    int b = bid / (11 * MSLICE);
    int c = threadIdx.x & 63, sub = threadIdx.x >> 6;

    const float* base; int stride;
    if (k == 0)      { base = x  + c;                stride = 64;  }
    else if (k <= 4) { base = S1 + (k - 1) * 64 + c; stride = 256; }
    else             { base = S2 + (k - 5) * 64 + c; stride = 384; }

    int s0 = boff[b], s1e = boff[b + 1];
    int cntb = s1e - s0;
    int per = (cntb + MSLICE - 1) / MSLICE;
    int i0 = s0 + slice * per;
    int i1 = min(s1e, i0 + per);

    double a1 = 0, a2 = 0, a3 = 0, a4 = 0;
    for (int i = i0 + sub; i < i1; i += 4) {
        double v = (double)base[(size_t)i * stride];
        double qq = v * v;
        a1 += v; a2 += qq; a3 += qq * v; a4 += qq * qq;
    }
    int fi = k * 64 + c;
    double* qp = part + ((((size_t)slice * 4 + sub) * NB + b) * NFEAT + fi) * 4;
    qp[0] = a1; qp[1] = a2; qp[2] = a3; qp[3] = a4;
}

__global__ void finalize_k(const double* __restrict__ part, const int* __restrict__ boff,
                           const float* __restrict__ W, float* __restrict__ out) {
    int i = blockIdx.x * blockDim.x + threadIdx.x;
    if (i < NB * NFEAT) {
        int b = i / NFEAT, fi = i % NFEAT;
        double s1 = 0, s2 = 0, s3 = 0, s4 = 0;
        for (int s = 0; s < PSLICE; ++s) {
            const double* qp = part + (((size_t)s * NB + b) * NFEAT + fi) * 4;
            s1 += qp[0]; s2 += qp[1]; s3 += qp[2]; s4 += qp[3];
        }
        double cn = (double)max(boff[b + 1] - boff[b], 1);
        double mean = s1 / cn;
        double e2 = s2 / cn, e3 = s3 / cn, e4 = s4 / cn;
        double var = e2 - mean * mean;
        double m3 = e3 - 3.0 * mean * e2 + 2.0 * mean * mean * mean;
        double m4 = e4 - 4.0 * mean * e3 + 6.0 * mean * mean * e2 - 3.0 * mean * mean * mean * mean;
        float skew, kurt;
        if (var > 0.0) {
            double vs = var * sqrt(var);
            skew = (float)(m3 / vs);
            kurt = (float)(m4 / (var * var));
        } else {
            skew = 0.f; kurt = -3.f;
        }
        out[b * 2816 + fi]        = (float)mean;
        out[b * 2816 + 704 + fi]  = (float)var;
        out[b * 2816 + 1408 + fi] = skew;
        out[b * 2816 + 2112 + fi] = kurt;
    } else if (i < NB * NFEAT + 68) {
        int j = i - NB * NFEAT;
        out[NB * 2816 + j] = W[j];
    }
}

// ---------------- launch ----------------

extern "C" void kernel_launch(void* const* d_in, const int* in_sizes, int n_in,
                              void* d_out, int out_size, void* d_ws, size_t ws_size,
                              hipStream_t stream) {
    const float* x     = (const float*)d_in[0];
    const int*   ei    = (const int*)d_in[1];
    const int*   batch = (const int*)d_in[2];
    const float* W     = (const float*)d_in[3];
    int N = in_sizes[0] / 64;   // 20000
    int E = in_sizes[1] / 2;    // 640000
    float* out = (float*)d_out;

    char* p = (char*)d_ws;
    auto alloc = [&](size_t bytes) { char* r = p; p += (bytes + 255) & ~255ULL; return r; };
    float* dinv  = (float*)alloc((size_t)N * 4);
    int*   cnt   = (int*)alloc((size_t)N * 4);
    int*   cursor= (int*)alloc((size_t)N * 4);
    int*   boff  = (int*)alloc((NB + 1) * 4);
    int*   bar   = (int*)alloc(256);
    double* part = (double*)alloc((size_t)PSLICE * NB * NFEAT * 4 * 8);
    unsigned int* pairs = (unsigned int*)alloc((size_t)N * CAP * 4);
    float* S1    = (float*)alloc((size_t)N * 256 * 4);
    float* S2    = (float*)alloc((size_t)N * 384 * 4);
    long nu = (long)N * 64;
    unsigned short* xh  = (unsigned short*)alloc((size_t)nu * 2);
    unsigned short* m1a = (unsigned short*)alloc((size_t)nu * 2);
    unsigned short* m1b = (unsigned short*)alloc((size_t)nu * 2);
    unsigned short* s1h = (unsigned short*)alloc((size_t)3 * nu * 2);
    unsigned short* m2a = (unsigned short*)alloc((size_t)3 * nu * 2);
    unsigned short* m2b = (unsigned short*)alloc((size_t)3 * nu * 2);

    hipMemsetAsync(cnt, 0, (size_t)N * 4, stream);
    hipMemsetAsync(cursor, 0, (size_t)N * 4, stream);
    hipMemsetAsync(bar, 0, 256, stream);

    count_edges<<<(E + 255) / 256, 256, 0, stream>>>(ei, E, cnt);
    compute_dinv<<<(N + 255) / 256, 256, 0, stream>>>(cnt, dinv, N);
    fill_edges<<<(E + 255) / 256, 256, 0, stream>>>(ei, E, dinv, cursor, pairs);
    batch_bounds<<<(N + 255) / 256, 256, 0, stream>>>(batch, N, boff);
    convert_f16<<<((int)nu + 255) / 256, 256, 0, stream>>>(x, xh, (int)nu);

    persist_k<<<NBLK, 256, 0, stream>>>(x, xh, m1a, m1b, s1h, m2a, m2b,
                                        S1, S2, pairs, cnt, dinv, N, bar);

    moments_part<<<NB * 11 * MSLICE, 256, 0, stream>>>(x, S1, S2, boff, part);

    int fin_threads = NB * NFEAT + 68;
    finalize_k<<<(fin_threads + 255) / 256, 256, 0, stream>>>(part, boff, W, out);
}

// Round 13
// 1152.863 us; speedup vs baseline: 2.8718x; 2.8718x over previous
//
#include <hip/hip_runtime.h>
#include <hip/hip_fp16.h>

#define NB 8
#define CAP 128
#define NFEAT 704
#define MSLICE 8            // node slices per (batch,k) in moments
#define PSLICE (MSLICE * 4) // partial slots = slices * subs

// ---------------- setup kernels ----------------

__global__ void count_edges(const int* __restrict__ ei, int E, int* __restrict__ cnt) {
    int e = blockIdx.x * blockDim.x + threadIdx.x;
    if (e < E) atomicAdd(&cnt[ei[E + e]], 1);
}

__global__ void compute_dinv(const int* __restrict__ cnt, float* __restrict__ dinv, int n) {
    int v = blockIdx.x * blockDim.x + threadIdx.x;
    if (v < n) dinv[v] = rsqrtf((float)(cnt[v] + 1));  // +1 self-loop; always > 0
}

// packed edge: low 16 = src node (N < 65536), high 16 = f16 weight
__global__ void fill_edges(const int* __restrict__ ei, int E, const float* __restrict__ dinv,
                           int* __restrict__ cursor, unsigned int* __restrict__ pairs) {
    int e = blockIdx.x * blockDim.x + threadIdx.x;
    if (e < E) {
        int r = ei[e], c = ei[E + e];
        int pos = atomicAdd(&cursor[c], 1);
        if (pos < CAP) {
            float w = dinv[r] * dinv[c];
            __half hw = __float2half_rn(w);
            unsigned short hb = *reinterpret_cast<unsigned short*>(&hw);
            pairs[(size_t)c * CAP + pos] = (unsigned int)(r & 0xFFFF) | ((unsigned int)hb << 16);
        }
    }
}

// pad each node's edge list to a multiple of 8 with zero-weight edges (src 0, w +0)
__global__ void pad_edges(const int* __restrict__ cnt, unsigned int* __restrict__ pairs, int n) {
    int v = blockIdx.x * blockDim.x + threadIdx.x;
    if (v >= n) return;
    int c = min(cnt[v], CAP);
    int c8 = (c + 7) & ~7;
    for (int j = c; j < c8; ++j) pairs[(size_t)v * CAP + j] = 0u;
}

// batch is SORTED: boundaries, no atomics
__global__ void batch_bounds(const int* __restrict__ batch, int n, int* __restrict__ boff) {
    int i = blockIdx.x * blockDim.x + threadIdx.x;
    if (i >= n) return;
    int b = batch[i];
    int pb = (i == 0) ? -1 : batch[i - 1];
    for (int k = pb + 1; k <= b; ++k) boff[k] = i;
    if (i == n - 1) {
        for (int k = b + 1; k <= NB; ++k) boff[k] = n;
    }
}

__global__ void convert_f16(const float* __restrict__ x, unsigned short* __restrict__ xh, int n) {
    int i = blockIdx.x * blockDim.x + threadIdx.x;
    if (i < n) {
        __half h = __float2half_rn(x[i]);
        xh[i] = *reinterpret_cast<unsigned short*>(&h);
    }
}

// ---------------- cascade (ONE 64-ch unit per dispatch, one wave per node) ----------------
// h_out = 0.5*((1+dinv^2)*h_in + sum w*h_in[src]); gathers read the fp16 MIRROR of
// h_in (128 B row = 2 lines/edge); self term, state, diffs fp32.
// Exactly ONE mirror (2.5 MB) is gathered per dispatch -> fits per-XCD L2 next to
// its pair slice; this is the phase-A regime (~8 us/unit-step in R10) applied to all
// 64 unit-steps. Lane l: edge-phase sub = l>>4, channel quad cg = l&15 (uint2 = 4
// halves/gather). Pair group of 8 edges (two uint4) prefetched one round ahead.
// mode: 0 none, 1 snapshot (prev = v), 2 diff (|v - prev| -> Sdst[slot], prev = v).
// Shdst != nullptr: also write the diff as fp16 (births the L2 cascades from S1).

__device__ __forceinline__ float h2f16(unsigned short h) {
    __half hh = *reinterpret_cast<__half*>(&h);
    return __half2float(hh);
}

__device__ __forceinline__ void fma_h4(float w, uint2 m, float* a) {
    float2 f0 = __half22float2(*reinterpret_cast<__half2*>(&m.x));
    float2 f1 = __half22float2(*reinterpret_cast<__half2*>(&m.y));
    a[0] += w * f0.x; a[1] += w * f0.y; a[2] += w * f1.x; a[3] += w * f1.y;
}

__device__ __forceinline__ uint2 pack_h4(float4 v) {
    __half2 p01 = __float22half2_rn(make_float2(v.x, v.y));
    __half2 p23 = __float22half2_rn(make_float2(v.z, v.w));
    uint2 r;
    r.x = *reinterpret_cast<unsigned int*>(&p01);
    r.y = *reinterpret_cast<unsigned int*>(&p23);
    return r;
}

__global__ __launch_bounds__(256) void cascade1(
    const float* __restrict__ selfp, int sstride,
    const unsigned short* __restrict__ mirp,
    float* __restrict__ stateo, unsigned short* __restrict__ miro,
    float* __restrict__ prevb,
    const unsigned int* __restrict__ pairs, const int* __restrict__ cnt,
    const float* __restrict__ dinv, int n,
    int mode, int slot,
    float* __restrict__ Sdst, int sostride,
    unsigned short* __restrict__ Shdst)
{
    int lane = threadIdx.x & 63, widx = threadIdx.x >> 6;
    int node = blockIdx.x * 4 + widx;
    if (node >= n) return;
    node = __builtin_amdgcn_readfirstlane(node);

    int deg = min(cnt[node], CAP);
    int deg8 = (deg + 7) & ~7;
    float dv = dinv[node];
    float selfw = 1.f + dv * dv;

    int sub = lane >> 4;   // edge within group of 4
    int cg  = lane & 15;   // channel quad: ch cg*4 .. +3

    const unsigned int* pb = pairs + (size_t)node * CAP;

    float a[4] = {0.f, 0.f, 0.f, 0.f};

    if (deg8 > 0) {
        uint4 qA = *reinterpret_cast<const uint4*>(pb);
        uint4 qB = *reinterpret_cast<const uint4*>(pb + 4);
        int j = 0;
        while (true) {
            int jn = j + 8;
            bool more = jn < deg8;
            uint4 nA, nB;
            if (more) {  // prefetch next pair group before consuming this one
                nA = *reinterpret_cast<const uint4*>(pb + jn);
                nB = *reinterpret_cast<const uint4*>(pb + jn + 4);
            }
            unsigned int eA = sub < 2 ? (sub == 0 ? qA.x : qA.y) : (sub == 2 ? qA.z : qA.w);
            unsigned int eB = sub < 2 ? (sub == 0 ? qB.x : qB.y) : (sub == 2 ? qB.z : qB.w);
            int   sA = (int)(eA & 0xFFFFu);
            float wA = h2f16((unsigned short)(eA >> 16));
            int   sB = (int)(eB & 0xFFFFu);
            float wB = h2f16((unsigned short)(eB >> 16));
            uint2 gA = *reinterpret_cast<const uint2*>(mirp + (size_t)sA * 64 + cg * 4);
            uint2 gB = *reinterpret_cast<const uint2*>(mirp + (size_t)sB * 64 + cg * 4);
            fma_h4(wA, gA, a);
            fma_h4(wB, gB, a);
            if (!more) break;
            qA = nA; qB = nB; j = jn;
        }
    }

    // reduce the 4 edge-phases: lanes {cg, cg+16, cg+32, cg+48} share channels
#pragma unroll
    for (int m = 16; m <= 32; m <<= 1) {
#pragma unroll
        for (int k = 0; k < 4; ++k) a[k] += __shfl_xor(a[k], m, 64);
    }

    if (lane < 16) {
        float4 hv = *reinterpret_cast<const float4*>(selfp + (size_t)node * sstride + cg * 4);
        float4 v;
        v.x = 0.5f * (selfw * hv.x + a[0]);
        v.y = 0.5f * (selfw * hv.y + a[1]);
        v.z = 0.5f * (selfw * hv.z + a[2]);
        v.w = 0.5f * (selfw * hv.w + a[3]);
        size_t oidx = (size_t)node * 64 + cg * 4;
        *reinterpret_cast<float4*>(stateo + oidx) = v;
        *reinterpret_cast<uint2*>(miro + oidx) = pack_h4(v);
        float* prow = prevb + oidx;
        if (mode == 1) {
            *reinterpret_cast<float4*>(prow) = v;
        } else if (mode == 2) {
            float4 pv = *reinterpret_cast<const float4*>(prow);
            *reinterpret_cast<float4*>(prow) = v;
            float4 d;
            d.x = fabsf(v.x - pv.x); d.y = fabsf(v.y - pv.y);
            d.z = fabsf(v.z - pv.z); d.w = fabsf(v.w - pv.w);
            *reinterpret_cast<float4*>(Sdst + (size_t)node * sostride + slot * 64 + cg * 4) = d;
            if (Shdst)
                *reinterpret_cast<uint2*>(Shdst + oidx) = pack_h4(d);
        }
    }
}

// ---------------- moments (coalesced two-stage, no atomics) ----------------

__global__ __launch_bounds__(256) void moments_part(
    const float* __restrict__ x, const float* __restrict__ S1,
    const float* __restrict__ S2, const int* __restrict__ boff,
    double* __restrict__ part)
{
    int bid = blockIdx.x;                    // b * (11*MSLICE) + k * MSLICE + slice
    int slice = bid % MSLICE;
    int k = (bid / MSLICE) % 11;
    int b = bid / (11 * MSLICE);
    int c = threadIdx.x & 63, sub = threadIdx.x >> 6;

    const float* base; int stride;
    if (k == 0)      { base = x  + c;                stride = 64;  }
    else if (k <= 4) { base = S1 + (k - 1) * 64 + c; stride = 256; }
    else             { base = S2 + (k - 5) * 64 + c; stride = 384; }

    int s0 = boff[b], s1e = boff[b + 1];
    int cntb = s1e - s0;
    int per = (cntb + MSLICE - 1) / MSLICE;
    int i0 = s0 + slice * per;
    int i1 = min(s1e, i0 + per);

    double a1 = 0, a2 = 0, a3 = 0, a4 = 0;
    for (int i = i0 + sub; i < i1; i += 4) {
        double v = (double)base[(size_t)i * stride];
        double qq = v * v;
        a1 += v; a2 += qq; a3 += qq * v; a4 += qq * qq;
    }
    int f = k * 64 + c;
    double* qp = part + ((((size_t)slice * 4 + sub) * NB + b) * NFEAT + f) * 4;
    qp[0] = a1; qp[1] = a2; qp[2] = a3; qp[3] = a4;
}

__global__ void finalize_k(const double* __restrict__ part, const int* __restrict__ boff,
                           const float* __restrict__ W, float* __restrict__ out) {
    int i = blockIdx.x * blockDim.x + threadIdx.x;
    if (i < NB * NFEAT) {
        int b = i / NFEAT, f = i % NFEAT;
        double s1 = 0, s2 = 0, s3 = 0, s4 = 0;
        for (int s = 0; s < PSLICE; ++s) {
            const double* qp = part + (((size_t)s * NB + b) * NFEAT + f) * 4;
            s1 += qp[0]; s2 += qp[1]; s3 += qp[2]; s4 += qp[3];
        }
        double cn = (double)max(boff[b + 1] - boff[b], 1);
        double mean = s1 / cn;
        double e2 = s2 / cn, e3 = s3 / cn, e4 = s4 / cn;
        double var = e2 - mean * mean;
        double m3 = e3 - 3.0 * mean * e2 + 2.0 * mean * mean * mean;
        double m4 = e4 - 4.0 * mean * e3 + 6.0 * mean * mean * e2 - 3.0 * mean * mean * mean * mean;
        float skew, kurt;
        if (var > 0.0) {
            double vs = var * sqrt(var);
            skew = (float)(m3 / vs);
            kurt = (float)(m4 / (var * var));
        } else {
            skew = 0.f; kurt = -3.f;
        }
        out[b * 2816 + f]        = (float)mean;
        out[b * 2816 + 704 + f]  = (float)var;
        out[b * 2816 + 1408 + f] = skew;
        out[b * 2816 + 2112 + f] = kurt;
    } else if (i < NB * NFEAT + 68) {
        int j = i - NB * NFEAT;
        out[NB * 2816 + j] = W[j];
    }
}

// ---------------- launch ----------------

extern "C" void kernel_launch(void* const* d_in, const int* in_sizes, int n_in,
                              void* d_out, int out_size, void* d_ws, size_t ws_size,
                              hipStream_t stream) {
    const float* x     = (const float*)d_in[0];
    const int*   ei    = (const int*)d_in[1];
    const int*   batch = (const int*)d_in[2];
    const float* W     = (const float*)d_in[3];
    int N = in_sizes[0] / 64;   // 20000
    int E = in_sizes[1] / 2;    // 640000
    float* out = (float*)d_out;

    char* p = (char*)d_ws;
    auto alloc = [&](size_t bytes) { char* r = p; p += (bytes + 255) & ~255ULL; return r; };
    float* dinv  = (float*)alloc((size_t)N * 4);
    int*   cnt   = (int*)alloc((size_t)N * 4);
    int*   cursor= (int*)alloc((size_t)N * 4);
    int*   boff  = (int*)alloc((NB + 1) * 4);
    double* part = (double*)alloc((size_t)PSLICE * NB * NFEAT * 4 * 8);
    unsigned int* pairs = (unsigned int*)alloc((size_t)N * CAP * 4);
    float* S1    = (float*)alloc((size_t)N * 256 * 4);
    float* S2    = (float*)alloc((size_t)N * 384 * 4);
    long nu = (long)N * 64;
    unsigned short* s1h = (unsigned short*)alloc((size_t)3 * nu * 2);
    unsigned short* xh  = (unsigned short*)alloc((size_t)nu * 2);
    float* bA    = (float*)alloc((size_t)nu * 4);
    float* bB    = (float*)alloc((size_t)nu * 4);
    unsigned short* hA = (unsigned short*)alloc((size_t)nu * 2);
    unsigned short* hB = (unsigned short*)alloc((size_t)nu * 2);
    float* prev  = (float*)alloc((size_t)nu * 4);

    hipMemsetAsync(cnt, 0, (size_t)N * 4, stream);
    hipMemsetAsync(cursor, 0, (size_t)N * 4, stream);

    count_edges<<<(E + 255) / 256, 256, 0, stream>>>(ei, E, cnt);
    compute_dinv<<<(N + 255) / 256, 256, 0, stream>>>(cnt, dinv, N);
    fill_edges<<<(E + 255) / 256, 256, 0, stream>>>(ei, E, dinv, cursor, pairs);
    pad_edges<<<(N + 255) / 256, 256, 0, stream>>>(cnt, pairs, N);
    batch_bounds<<<(N + 255) / 256, 256, 0, stream>>>(batch, N, boff);
    convert_f16<<<((int)nu + 255) / 256, 256, 0, stream>>>(x, xh, (int)nu);

    int cgrid = (N + 3) / 4;

    // ---- level 1: 16 unit-steps on x; snap s=1; diffs {2,4,8,16} -> S1 slots 0..3,
    //      slots 0..2 also mirrored to f16 s1h (birth of the L2 cascades) ----
    for (int s = 1; s <= 16; ++s) {
        const float* si = (s == 1) ? x  : ((s & 1) ? bB : bA);
        const unsigned short* mi = (s == 1) ? xh : ((s & 1) ? hB : hA);
        float* so = (s & 1) ? bA : bB;
        unsigned short* mo = (s & 1) ? hA : hB;
        int mode = 0, slot = 0;
        if (s == 1) mode = 1;
        else if (s == 2 || s == 4 || s == 8 || s == 16) {
            mode = 2;
            slot = (s == 2) ? 0 : (s == 4) ? 1 : (s == 8) ? 2 : 3;
        }
        unsigned short* shd = (mode == 2 && slot < 3) ? (s1h + (size_t)slot * nu) : nullptr;
        cascade1<<<cgrid, 256, 0, stream>>>(si, (s == 1) ? 64 : 64, mi, so, mo, prev,
                                            pairs, cnt, dinv, N, mode, slot, S1, 256, shd);
    }

    // ---- level 2: 3 units sequentially, 16 unit-steps each; unit u: snap f=2<<u,
    //      diffs f in {4,8,16} with f>snap -> S2 slots ----
    for (int u = 0; u < 3; ++u) {
        int snap = 2 << u;
        for (int f = 1; f <= 16; ++f) {
            const float* si; int sstride;
            const unsigned short* mi;
            if (f == 1) { si = S1 + u * 64; sstride = 256; mi = s1h + (size_t)u * nu; }
            else        { si = (f & 1) ? bB : bA; sstride = 64; mi = (f & 1) ? hB : hA; }
            float* so = (f & 1) ? bA : bB;
            unsigned short* mo = (f & 1) ? hA : hB;
            int mode = 0, slot = 0;
            if (f == snap) mode = 1;
            else if (f > snap && (f == 4 || f == 8 || f == 16)) {
                mode = 2;
                if (u == 0)      slot = (f == 4) ? 0 : (f == 8) ? 1 : 3;
                else if (u == 1) slot = (f == 8) ? 2 : 4;
                else             slot = 5;
            }
            cascade1<<<cgrid, 256, 0, stream>>>(si, sstride, mi, so, mo, prev,
                                                pairs, cnt, dinv, N, mode, slot, S2, 384, nullptr);
        }
    }

    moments_part<<<NB * 11 * MSLICE, 256, 0, stream>>>(x, S1, S2, boff, part);

    int fin_threads = NB * NFEAT + 68;
    finalize_k<<<(fin_threads + 255) / 256, 256, 0, stream>>>(part, boff, W, out);
}

// Round 14
// 888.968 us; speedup vs baseline: 3.7243x; 1.2969x over previous
//
#include <hip/hip_runtime.h>
#include <hip/hip_fp16.h>

#define NB 8
#define CAP 128
#define NFEAT 704
#define MSLICE 16           // node slices per (batch,k) in moments
#define PSLICE (MSLICE * 4) // partial slots = slices * subs

// ---------------- setup kernels ----------------

__global__ void count_edges(const int* __restrict__ ei, int E, int* __restrict__ cnt) {
    int e = blockIdx.x * blockDim.x + threadIdx.x;
    if (e < E) atomicAdd(&cnt[ei[E + e]], 1);
}

__global__ void compute_dinv(const int* __restrict__ cnt, float* __restrict__ dinv, int n) {
    int v = blockIdx.x * blockDim.x + threadIdx.x;
    if (v < n) dinv[v] = rsqrtf((float)(cnt[v] + 1));  // +1 self-loop; always > 0
}

// packed edge: low 16 = src node (N < 65536), high 16 = f16 weight
__global__ void fill_edges(const int* __restrict__ ei, int E, const float* __restrict__ dinv,
                           int* __restrict__ cursor, unsigned int* __restrict__ pairs) {
    int e = blockIdx.x * blockDim.x + threadIdx.x;
    if (e < E) {
        int r = ei[e], c = ei[E + e];
        int pos = atomicAdd(&cursor[c], 1);
        if (pos < CAP) {
            float w = dinv[r] * dinv[c];
            __half hw = __float2half_rn(w);
            unsigned short hb = *reinterpret_cast<unsigned short*>(&hw);
            pairs[(size_t)c * CAP + pos] = (unsigned int)(r & 0xFFFF) | ((unsigned int)hb << 16);
        }
    }
}

// pad each node's edge list to a multiple of 8 with zero-weight edges (src 0, w +0)
__global__ void pad_edges(const int* __restrict__ cnt, unsigned int* __restrict__ pairs, int n) {
    int v = blockIdx.x * blockDim.x + threadIdx.x;
    if (v >= n) return;
    int c = min(cnt[v], CAP);
    int c8 = (c + 7) & ~7;
    for (int j = c; j < c8; ++j) pairs[(size_t)v * CAP + j] = 0u;
}

// batch is SORTED: boundaries, no atomics
__global__ void batch_bounds(const int* __restrict__ batch, int n, int* __restrict__ boff) {
    int i = blockIdx.x * blockDim.x + threadIdx.x;
    if (i >= n) return;
    int b = batch[i];
    int pb = (i == 0) ? -1 : batch[i - 1];
    for (int k = pb + 1; k <= b; ++k) boff[k] = i;
    if (i == n - 1) {
        for (int k = b + 1; k <= NB; ++k) boff[k] = n;
    }
}

__global__ void convert_f16(const float* __restrict__ x, unsigned short* __restrict__ xh, int n) {
    int i = blockIdx.x * blockDim.x + threadIdx.x;
    if (i < n) {
        __half h = __float2half_rn(x[i]);
        xh[i] = *reinterpret_cast<unsigned short*>(&h);
    }
}

// ---------------- cascade (U1 L1-units + U2 L2-units per wave, one wave per node) --------
// h_out = 0.5*((1+dinv^2)*h_in + sum w*h_in[src]); gathers read fp16 MIRRORS
// (128 B/row/unit); self term, state, diffs fp32. Lane l: edge-phase sub=l>>4,
// channel quad cg=l&15 (uint2 = 4 halves/gather). Packed 4 B pairs loaded once
// per wave, shared by all U1+U2 units; next 8-edge pair group PREFETCHED before
// the current group's gathers (breaks pair->gather serial chain).
// L1 snap s=1, diffs {2,4,8,16}->S1 slots 0..3 (+f16 S1h slots 0..2).
// L2 unit u: snap s=2<<u, diffs later {4,8,16}->S2 slots.
// Instantiations: <1,0> L1-only, <1,3> fused (L1 step s1 = s2+8), <0,3> L2-only.

__device__ __forceinline__ float h2f16(unsigned short h) {
    __half hh = *reinterpret_cast<__half*>(&h);
    return __half2float(hh);
}

__device__ __forceinline__ void fma_h4(float w, uint2 m, float* a) {
    float2 f0 = __half22float2(*reinterpret_cast<__half2*>(&m.x));
    float2 f1 = __half22float2(*reinterpret_cast<__half2*>(&m.y));
    a[0] += w * f0.x; a[1] += w * f0.y; a[2] += w * f1.x; a[3] += w * f1.y;
}

__device__ __forceinline__ uint2 pack_h4(float4 v) {
    __half2 p01 = __float22half2_rn(make_float2(v.x, v.y));
    __half2 p23 = __float22half2_rn(make_float2(v.z, v.w));
    uint2 r;
    r.x = *reinterpret_cast<unsigned int*>(&p01);
    r.y = *reinterpret_cast<unsigned int*>(&p23);
    return r;
}

template <int U1, int U2>
__global__ __launch_bounds__(256) void cascade_k(
    const float* __restrict__ self1, const unsigned short* __restrict__ mir1,
    float* __restrict__ state1o, unsigned short* __restrict__ mir1o,
    float* __restrict__ prev1, int s1,
    const float* __restrict__ self2, int sstride2, long usz2,
    const unsigned short* __restrict__ mir2, long musz2,
    float* __restrict__ state2o, unsigned short* __restrict__ mir2o,
    float* __restrict__ prev2, int s2,
    const unsigned int* __restrict__ pairs, const int* __restrict__ cnt,
    const float* __restrict__ dinv, int n,
    float* __restrict__ S1, unsigned short* __restrict__ S1h,
    float* __restrict__ S2)
{
    int lane = threadIdx.x & 63, widx = threadIdx.x >> 6;
    int node = blockIdx.x * 4 + widx;
    if (node >= n) return;
    node = __builtin_amdgcn_readfirstlane(node);

    int deg = min(cnt[node], CAP);
    int deg8 = (deg + 7) & ~7;
    float dv = dinv[node];
    float selfw = 1.f + dv * dv;

    int sub = lane >> 4;   // edge within group of 4
    int cg  = lane & 15;   // channel quad: ch cg*4 .. +3

    const unsigned int* pb = pairs + (size_t)node * CAP;

    float a1[U1 ? U1 : 1][4], a2[U2 ? U2 : 1][4];
#pragma unroll
    for (int u = 0; u < (U1 ? U1 : 1); ++u)
#pragma unroll
        for (int k = 0; k < 4; ++k) a1[u][k] = 0.f;
#pragma unroll
    for (int u = 0; u < (U2 ? U2 : 1); ++u)
#pragma unroll
        for (int k = 0; k < 4; ++k) a2[u][k] = 0.f;

    if (deg8 > 0) {
        uint4 qA = *reinterpret_cast<const uint4*>(pb);
        uint4 qB = *reinterpret_cast<const uint4*>(pb + 4);
        int j = 0;
        while (true) {
            int jn = j + 8;
            bool more = jn < deg8;
            uint4 nA, nB;
            if (more) {  // prefetch next pair group before consuming this one
                nA = *reinterpret_cast<const uint4*>(pb + jn);
                nB = *reinterpret_cast<const uint4*>(pb + jn + 4);
            }
            unsigned int eA = sub < 2 ? (sub == 0 ? qA.x : qA.y) : (sub == 2 ? qA.z : qA.w);
            unsigned int eB = sub < 2 ? (sub == 0 ? qB.x : qB.y) : (sub == 2 ? qB.z : qB.w);
            int   sA = (int)(eA & 0xFFFFu);
            float wA = h2f16((unsigned short)(eA >> 16));
            int   sB = (int)(eB & 0xFFFFu);
            float wB = h2f16((unsigned short)(eB >> 16));
            // issue all gathers, then all FMAs
            uint2 g1A, g1B, g2A[U2 ? U2 : 1], g2B[U2 ? U2 : 1];
            if (U1) {
                g1A = *reinterpret_cast<const uint2*>(mir1 + (size_t)sA * 64 + cg * 4);
                g1B = *reinterpret_cast<const uint2*>(mir1 + (size_t)sB * 64 + cg * 4);
            }
#pragma unroll
            for (int u = 0; u < U2; ++u)
                g2A[u] = *reinterpret_cast<const uint2*>(mir2 + (size_t)u * musz2 + (size_t)sA * 64 + cg * 4);
#pragma unroll
            for (int u = 0; u < U2; ++u)
                g2B[u] = *reinterpret_cast<const uint2*>(mir2 + (size_t)u * musz2 + (size_t)sB * 64 + cg * 4);
            if (U1) { fma_h4(wA, g1A, a1[0]); fma_h4(wB, g1B, a1[0]); }
#pragma unroll
            for (int u = 0; u < U2; ++u) {
                fma_h4(wA, g2A[u], a2[u]);
                fma_h4(wB, g2B[u], a2[u]);
            }
            if (!more) break;
            qA = nA; qB = nB; j = jn;
        }
    }

    // reduce the 4 edge-phases: lanes {cg, cg+16, cg+32, cg+48} share channels
#pragma unroll
    for (int m = 16; m <= 32; m <<= 1) {
#pragma unroll
        for (int u = 0; u < U1; ++u)
#pragma unroll
            for (int k = 0; k < 4; ++k) a1[u][k] += __shfl_xor(a1[u][k], m, 64);
#pragma unroll
        for (int u = 0; u < U2; ++u)
#pragma unroll
            for (int k = 0; k < 4; ++k) a2[u][k] += __shfl_xor(a2[u][k], m, 64);
    }

    if (lane < 16) {
        if (U1) {
            float4 hv = *reinterpret_cast<const float4*>(self1 + (size_t)node * 64 + cg * 4);
            float4 v;
            v.x = 0.5f * (selfw * hv.x + a1[0][0]);
            v.y = 0.5f * (selfw * hv.y + a1[0][1]);
            v.z = 0.5f * (selfw * hv.z + a1[0][2]);
            v.w = 0.5f * (selfw * hv.w + a1[0][3]);
            size_t oidx = (size_t)node * 64 + cg * 4;
            *reinterpret_cast<float4*>(state1o + oidx) = v;
            *reinterpret_cast<uint2*>(mir1o + oidx) = pack_h4(v);
            float* prow = prev1 + oidx;
            if (s1 == 1) {
                *reinterpret_cast<float4*>(prow) = v;
            } else if (s1 == 2 || s1 == 4 || s1 == 8 || s1 == 16) {
                float4 pv = *reinterpret_cast<const float4*>(prow);
                *reinterpret_cast<float4*>(prow) = v;
                float4 d;
                d.x = fabsf(v.x - pv.x); d.y = fabsf(v.y - pv.y);
                d.z = fabsf(v.z - pv.z); d.w = fabsf(v.w - pv.w);
                int slot = (s1 == 2) ? 0 : (s1 == 4) ? 1 : (s1 == 8) ? 2 : 3;
                *reinterpret_cast<float4*>(S1 + (size_t)node * 256 + slot * 64 + cg * 4) = d;
                if (slot < 3)
                    *reinterpret_cast<uint2*>(S1h + (size_t)slot * n * 64 + oidx) = pack_h4(d);
            }
        }
#pragma unroll
        for (int u = 0; u < U2; ++u) {
            const float* srow = self2 + (size_t)u * usz2 + (size_t)node * sstride2 + cg * 4;
            float4 hv = *reinterpret_cast<const float4*>(srow);
            float4 v;
            v.x = 0.5f * (selfw * hv.x + a2[u][0]);
            v.y = 0.5f * (selfw * hv.y + a2[u][1]);
            v.z = 0.5f * (selfw * hv.z + a2[u][2]);
            v.w = 0.5f * (selfw * hv.w + a2[u][3]);
            size_t oidx = (size_t)u * n * 64 + (size_t)node * 64 + cg * 4;
            *reinterpret_cast<float4*>(state2o + oidx) = v;
            *reinterpret_cast<uint2*>(mir2o + oidx) = pack_h4(v);
            int snap = 2 << u;
            float* prow = prev2 + oidx;
            if (s2 == snap) {
                *reinterpret_cast<float4*>(prow) = v;
            } else if (s2 > snap && (s2 == 4 || s2 == 8 || s2 == 16)) {
                float4 pv = *reinterpret_cast<const float4*>(prow);
                *reinterpret_cast<float4*>(prow) = v;
                float4 d;
                d.x = fabsf(v.x - pv.x); d.y = fabsf(v.y - pv.y);
                d.z = fabsf(v.z - pv.z); d.w = fabsf(v.w - pv.w);
                int slt;
                if (u == 0)      slt = (s2 == 4) ? 0 : (s2 == 8) ? 1 : 3;
                else if (u == 1) slt = (s2 == 8) ? 2 : 4;
                else             slt = 5;
                *reinterpret_cast<float4*>(S2 + (size_t)node * 384 + slt * 64 + cg * 4) = d;
            }
        }
    }
}

// ---------------- moments (coalesced two-stage, no atomics) ----------------

__global__ __launch_bounds__(256) void moments_part(
    const float* __restrict__ x, const float* __restrict__ S1,
    const float* __restrict__ S2, const int* __restrict__ boff,
    double* __restrict__ part)
{
    int bid = blockIdx.x;                    // b * (11*MSLICE) + k * MSLICE + slice
    int slice = bid % MSLICE;
    int k = (bid / MSLICE) % 11;
    int b = bid / (11 * MSLICE);
    int c = threadIdx.x & 63, sub = threadIdx.x >> 6;

    const float* base; int stride;
    if (k == 0)      { base = x  + c;                stride = 64;  }
    else if (k <= 4) { base = S1 + (k - 1) * 64 + c; stride = 256; }
    else             { base = S2 + (k - 5) * 64 + c; stride = 384; }

    int s0 = boff[b], s1e = boff[b + 1];
    int cntb = s1e - s0;
    int per = (cntb + MSLICE - 1) / MSLICE;
    int i0 = s0 + slice * per;
    int i1 = min(s1e, i0 + per);

    double a1 = 0, a2 = 0, a3 = 0, a4 = 0;
    for (int i = i0 + sub; i < i1; i += 4) {
        double v = (double)base[(size_t)i * stride];
        double qq = v * v;
        a1 += v; a2 += qq; a3 += qq * v; a4 += qq * qq;
    }
    int f = k * 64 + c;
    double* qp = part + ((((size_t)slice * 4 + sub) * NB + b) * NFEAT + f) * 4;
    qp[0] = a1; qp[1] = a2; qp[2] = a3; qp[3] = a4;
}

__global__ void finalize_k(const double* __restrict__ part, const int* __restrict__ boff,
                           const float* __restrict__ W, float* __restrict__ out) {
    int i = blockIdx.x * blockDim.x + threadIdx.x;
    if (i < NB * NFEAT) {
        int b = i / NFEAT, f = i % NFEAT;
        double s1 = 0, s2 = 0, s3 = 0, s4 = 0;
        for (int s = 0; s < PSLICE; ++s) {
            const double* qp = part + (((size_t)s * NB + b) * NFEAT + f) * 4;
            s1 += qp[0]; s2 += qp[1]; s3 += qp[2]; s4 += qp[3];
        }
        double cn = (double)max(boff[b + 1] - boff[b], 1);
        double mean = s1 / cn;
        double e2 = s2 / cn, e3 = s3 / cn, e4 = s4 / cn;
        double var = e2 - mean * mean;
        double m3 = e3 - 3.0 * mean * e2 + 2.0 * mean * mean * mean;
        double m4 = e4 - 4.0 * mean * e3 + 6.0 * mean * mean * e2 - 3.0 * mean * mean * mean * mean;
        float skew, kurt;
        if (var > 0.0) {
            double vs = var * sqrt(var);
            skew = (float)(m3 / vs);
            kurt = (float)(m4 / (var * var));
        } else {
            skew = 0.f; kurt = -3.f;
        }
        out[b * 2816 + f]        = (float)mean;
        out[b * 2816 + 704 + f]  = (float)var;
        out[b * 2816 + 1408 + f] = skew;
        out[b * 2816 + 2112 + f] = kurt;
    } else if (i < NB * NFEAT + 68) {
        int j = i - NB * NFEAT;
        out[NB * 2816 + j] = W[j];
    }
}

// ---------------- launch ----------------

extern "C" void kernel_launch(void* const* d_in, const int* in_sizes, int n_in,
                              void* d_out, int out_size, void* d_ws, size_t ws_size,
                              hipStream_t stream) {
    const float* x     = (const float*)d_in[0];
    const int*   ei    = (const int*)d_in[1];
    const int*   batch = (const int*)d_in[2];
    const float* W     = (const float*)d_in[3];
    int N = in_sizes[0] / 64;   // 20000
    int E = in_sizes[1] / 2;    // 640000
    float* out = (float*)d_out;

    char* p = (char*)d_ws;
    auto alloc = [&](size_t bytes) { char* r = p; p += (bytes + 255) & ~255ULL; return r; };
    float* dinv  = (float*)alloc((size_t)N * 4);
    int*   cnt   = (int*)alloc((size_t)N * 4);
    int*   cursor= (int*)alloc((size_t)N * 4);
    int*   boff  = (int*)alloc((NB + 1) * 4);
    double* part = (double*)alloc((size_t)PSLICE * NB * NFEAT * 4 * 8);
    unsigned int* pairs = (unsigned int*)alloc((size_t)N * CAP * 4);
    float* S1    = (float*)alloc((size_t)N * 256 * 4);
    float* S2    = (float*)alloc((size_t)N * 384 * 4);
    unsigned short* S1h = (unsigned short*)alloc((size_t)3 * N * 64 * 2);
    unsigned short* xh  = (unsigned short*)alloc((size_t)N * 64 * 2);
    float* b1A   = (float*)alloc((size_t)N * 64 * 4);
    float* b1B   = (float*)alloc((size_t)N * 64 * 4);
    unsigned short* h1A = (unsigned short*)alloc((size_t)N * 64 * 2);
    unsigned short* h1B = (unsigned short*)alloc((size_t)N * 64 * 2);
    float* prev1 = (float*)alloc((size_t)N * 64 * 4);
    float* b2A   = (float*)alloc((size_t)3 * N * 64 * 4);
    float* b2B   = (float*)alloc((size_t)3 * N * 64 * 4);
    unsigned short* h2A = (unsigned short*)alloc((size_t)3 * N * 64 * 2);
    unsigned short* h2B = (unsigned short*)alloc((size_t)3 * N * 64 * 2);
    float* prev2 = (float*)alloc((size_t)3 * N * 64 * 4);

    hipMemsetAsync(cnt, 0, (size_t)N * 4, stream);
    hipMemsetAsync(cursor, 0, (size_t)N * 4, stream);

    count_edges<<<(E + 255) / 256, 256, 0, stream>>>(ei, E, cnt);
    compute_dinv<<<(N + 255) / 256, 256, 0, stream>>>(cnt, dinv, N);
    fill_edges<<<(E + 255) / 256, 256, 0, stream>>>(ei, E, dinv, cursor, pairs);
    pad_edges<<<(N + 255) / 256, 256, 0, stream>>>(cnt, pairs, N);
    batch_bounds<<<(N + 255) / 256, 256, 0, stream>>>(batch, N, boff);
    convert_f16<<<(N * 64 + 255) / 256, 256, 0, stream>>>(x, xh, N * 64);

    long nu = (long)N * 64;
    int cgrid = (N + 3) / 4;

    // ---- phase A: L1 steps 1..8 (snap s=1; diffs s=2,4,8 -> S1 slots 0..2 + S1h) ----
    for (int s = 1; s <= 8; ++s) {
        const float* si = (s == 1) ? x  : ((s & 1) ? b1B : b1A);
        const unsigned short* mi = (s == 1) ? xh : ((s & 1) ? h1B : h1A);
        float* so = (s & 1) ? b1A : b1B;
        unsigned short* mo = (s & 1) ? h1A : h1B;
        cascade_k<1, 0><<<cgrid, 256, 0, stream>>>(
            si, mi, so, mo, prev1, s,
            nullptr, 0, 0, nullptr, 0, nullptr, nullptr, nullptr, 0,
            pairs, cnt, dinv, N, S1, S1h, S2);
    }

    // ---- phase B: fused — L1 step t=f+8 with L2 step f, f=1..8 ----
    for (int f = 1; f <= 8; ++f) {
        int t = f + 8;
        const float* s1i = ((t - 1) & 1) ? b1A : b1B;
        const unsigned short* m1i = ((t - 1) & 1) ? h1A : h1B;
        float* s1o = (t & 1) ? b1A : b1B;
        unsigned short* m1o = (t & 1) ? h1A : h1B;
        const float* s2i; int sstride2; long usz2;
        const unsigned short* m2i; long musz2;
        if (f == 1) { s2i = S1; sstride2 = 256; usz2 = 64; m2i = S1h; musz2 = nu; }
        else {
            s2i = ((f - 1) & 1) ? b2A : b2B; sstride2 = 64; usz2 = nu;
            m2i = ((f - 1) & 1) ? h2A : h2B; musz2 = nu;
        }
        float* s2o = (f & 1) ? b2A : b2B;
        unsigned short* m2o = (f & 1) ? h2A : h2B;
        cascade_k<1, 3><<<cgrid, 256, 0, stream>>>(
            s1i, m1i, s1o, m1o, prev1, t,
            s2i, sstride2, usz2, m2i, musz2, s2o, m2o, prev2, f,
            pairs, cnt, dinv, N, S1, S1h, S2);
    }

    // ---- phase C: L2-only steps 9..16 (diffs at 16 -> S2 slots 3,4,5) ----
    for (int s = 9; s <= 16; ++s) {
        const float* s2i = ((s - 1) & 1) ? b2A : b2B;
        const unsigned short* m2i = ((s - 1) & 1) ? h2A : h2B;
        float* s2o = (s & 1) ? b2A : b2B;
        unsigned short* m2o = (s & 1) ? h2A : h2B;
        cascade_k<0, 3><<<cgrid, 256, 0, stream>>>(
            nullptr, nullptr, nullptr, nullptr, nullptr, 0,
            s2i, 64, nu, m2i, nu, s2o, m2o, prev2, s,
            pairs, cnt, dinv, N, S1, S1h, S2);
    }

    moments_part<<<NB * 11 * MSLICE, 256, 0, stream>>>(x, S1, S2, boff, part);

    int fin_threads = NB * NFEAT + 68;
    finalize_k<<<(fin_threads + 255) / 256, 256, 0, stream>>>(part, boff, W, out);
}